// Round 8
// baseline (234.237 us; speedup 1.0000x reference)
//
#include <hip/hip_runtime.h>

#define N_NODES 100000
#define N_EDGES 1600000
#define D 64

#define BN 128                              // nodes per bucket
#define NBUCK ((N_NODES + BN - 1) / BN)     // 782
#define HW 256                              // histogram/scatter chunks
#define HCH ((N_EDGES + HW - 1) / HW)       // 6250 edges per chunk
#define HLEN (NBUCK * HW)                   // 200192
#define NB1 196                             // ceil(HLEN/1024)
#define SMAX 5120                           // LDS edge capacity per bucket (mean 2048)
#define OVF 256                             // overflow list (never used in practice)

static __device__ __forceinline__ unsigned short f2bf(float f) {
    unsigned u = __float_as_uint(f);
    u += 0x7FFFu + ((u >> 16) & 1u);
    return (unsigned short)(u >> 16);
}
static __device__ __forceinline__ float bf2f(unsigned short h) {
    return __uint_as_float((unsigned)h << 16);
}

// ---------------- GEMM: support(bf16) = X @ W ----------------
__global__ __launch_bounds__(256) void gcn_gemm(const float* __restrict__ x,
                                                const float* __restrict__ w,
                                                unsigned short* __restrict__ support) {
    __shared__ float4 wsh[64 * 16];
    int tid = threadIdx.x;
    const float4* w4 = (const float4*)w;
    for (int i = tid; i < 64 * 16; i += 256) wsh[i] = w4[i];
    __syncthreads();

    int idx = blockIdx.x * 256 + tid;
    int rowpair = idx >> 4;
    int c4 = idx & 15;
    long r0 = (long)rowpair * 2;
    const float4* xr0 = (const float4*)(x + r0 * D);
    const float4* xr1 = (const float4*)(x + (r0 + 1) * D);

    float4 a0 = make_float4(0.f, 0.f, 0.f, 0.f);
    float4 a1 = make_float4(0.f, 0.f, 0.f, 0.f);
    #pragma unroll 4
    for (int k4 = 0; k4 < 16; ++k4) {
        float4 xv0 = xr0[k4];
        float4 xv1 = xr1[k4];
        float4 w0 = wsh[(4 * k4 + 0) * 16 + c4];
        float4 w1 = wsh[(4 * k4 + 1) * 16 + c4];
        float4 w2 = wsh[(4 * k4 + 2) * 16 + c4];
        float4 w3 = wsh[(4 * k4 + 3) * 16 + c4];
        a0 += w0 * xv0.x + w1 * xv0.y + w2 * xv0.z + w3 * xv0.w;
        a1 += w0 * xv1.x + w1 * xv1.y + w2 * xv1.z + w3 * xv1.w;
    }
    ushort4* s4 = (ushort4*)support;
    s4[r0 * 16 + c4] = make_ushort4(f2bf(a0.x), f2bf(a0.y), f2bf(a0.z), f2bf(a0.w));
    s4[(r0 + 1) * 16 + c4] = make_ushort4(f2bf(a1.x), f2bf(a1.y), f2bf(a1.z), f2bf(a1.w));
}

// ---------------- per-chunk histogram over buckets ----------------
__global__ __launch_bounds__(256) void gcn_hist(const int* __restrict__ dst,
                                                int* __restrict__ hist) {
    __shared__ int h[NBUCK];
    int tid = threadIdx.x;
    for (int i = tid; i < NBUCK; i += 256) h[i] = 0;
    __syncthreads();
    int w = blockIdx.x;
    int e0 = w * HCH, e1 = min(e0 + HCH, N_EDGES);
    for (int e = e0 + tid; e < e1; e += 256) {
        int d = __builtin_nontemporal_load(&dst[e]);
        atomicAdd(&h[d >> 7], 1);
    }
    __syncthreads();
    for (int c = tid; c < NBUCK; c += 256) hist[c * HW + w] = h[c];
}

// ---------------- exclusive scan of hist ----------------
#define SCAN_B 1024
__global__ __launch_bounds__(256) void gcn_scan1(const int* __restrict__ in,
                                                 int* __restrict__ outp,
                                                 int* __restrict__ bsums, int len) {
    __shared__ int sh[256];
    int tid = threadIdx.x;
    int base = blockIdx.x * SCAN_B + tid * 4;
    int v0 = (base + 0 < len) ? in[base + 0] : 0;
    int v1 = (base + 1 < len) ? in[base + 1] : 0;
    int v2 = (base + 2 < len) ? in[base + 2] : 0;
    int v3 = (base + 3 < len) ? in[base + 3] : 0;
    int local = v0 + v1 + v2 + v3;
    sh[tid] = local;
    __syncthreads();
    for (int off = 1; off < 256; off <<= 1) {
        int t = 0;
        if (tid >= off) t = sh[tid - off];
        __syncthreads();
        if (tid >= off) sh[tid] += t;
        __syncthreads();
    }
    int excl = sh[tid] - local;
    if (base + 0 < len) outp[base + 0] = excl;
    if (base + 1 < len) outp[base + 1] = excl + v0;
    if (base + 2 < len) outp[base + 2] = excl + v0 + v1;
    if (base + 3 < len) outp[base + 3] = excl + v0 + v1 + v2;
    if (tid == 255) bsums[blockIdx.x] = sh[255];
}

__global__ __launch_bounds__(256) void gcn_scan2(int* __restrict__ bsums) {
    __shared__ int sh[256];
    int tid = threadIdx.x;
    int orig = (tid < NB1) ? bsums[tid] : 0;
    sh[tid] = orig;
    __syncthreads();
    for (int off = 1; off < 256; off <<= 1) {
        int t = 0;
        if (tid >= off) t = sh[tid - off];
        __syncthreads();
        if (tid >= off) sh[tid] += t;
        __syncthreads();
    }
    if (tid < NB1) bsums[tid] = sh[tid] - orig;  // exclusive
}

__global__ __launch_bounds__(256) void gcn_scan3(int* __restrict__ data,
                                                 const int* __restrict__ bsums, int len) {
    int i = blockIdx.x * 256 + threadIdx.x;
    if (i < len) data[i] += bsums[i >> 10];
}

// ---------------- coarse scatter: bucket-sorted edges ----------------
__global__ __launch_bounds__(256) void gcn_coarse(const int* __restrict__ src,
                                                  const int* __restrict__ dst,
                                                  const float* __restrict__ adj,
                                                  const int* __restrict__ base,
                                                  int2* __restrict__ coarse) {
    __shared__ int cur[NBUCK];
    int tid = threadIdx.x;
    int w = blockIdx.x;
    for (int c = tid; c < NBUCK; c += 256) cur[c] = base[c * HW + w];
    __syncthreads();
    int e0 = w * HCH, e1 = min(e0 + HCH, N_EDGES);
    for (int e = e0 + tid; e < e1; e += 256) {
        int d = __builtin_nontemporal_load(&dst[e]);
        int s = __builtin_nontemporal_load(&src[e]);
        float a = __builtin_nontemporal_load(&adj[e]);
        int pos = atomicAdd(&cur[d >> 7], 1);
        coarse[pos] = make_int2(s | ((d & 127) << 17), __float_as_int(a));
    }
}

// ---------------- fused: per-bucket LDS counting sort + wide gather ----------------
__global__ __launch_bounds__(256) void gcn_bgather(const unsigned short* __restrict__ support,
                                                   const int2* __restrict__ coarse,
                                                   const int* __restrict__ base,
                                                   const float* __restrict__ bias,
                                                   float* __restrict__ out) {
    __shared__ int2 sE[SMAX];       // 40 KB sorted edges
    __shared__ int2 ovfE[OVF];      // 2 KB overflow (never used in practice)
    __shared__ int cntS[BN], loffS[BN], curS[BN];
    __shared__ int ovfN;

    int tid = threadIdx.x, wv = tid >> 6, lane = tid & 63;
    int b = blockIdx.x;
    int e0 = base[b * HW];
    int e1 = (b == NBUCK - 1) ? N_EDGES : base[(b + 1) * HW];

    if (tid < BN) cntS[tid] = 0;
    if (tid == 0) ovfN = 0;
    __syncthreads();

    // phase A: count per-node (normal loads -> window goes L2-resident)
    for (int e = e0 + tid; e < e1; e += 256)
        atomicAdd(&cntS[(coarse[e].x >> 17) & 127], 1);
    __syncthreads();

    // scan 128 counters
    if (tid < BN) loffS[tid] = cntS[tid];
    __syncthreads();
    for (int off = 1; off < BN; off <<= 1) {
        int t = 0;
        if (tid < BN && tid >= off) t = loffS[tid - off];
        __syncthreads();
        if (tid < BN && tid >= off) loffS[tid] += t;
        __syncthreads();
    }
    if (tid < BN) {
        int excl = loffS[tid] - cntS[tid];
        loffS[tid] = excl;
        curS[tid] = excl;
    }
    __syncthreads();

    // phase B: place edges into LDS per-node-sorted (window re-read hits L2)
    for (int e = e0 + tid; e < e1; e += 256) {
        int2 ed = coarse[e];
        int nl = (ed.x >> 17) & 127;
        int pos = atomicAdd(&curS[nl], 1);
        if (pos < SMAX) sE[pos] = ed;
        else {
            int op = atomicAdd(&ovfN, 1);
            if (op < OVF) ovfE[op] = ed;
        }
    }
    __syncthreads();

    // gather: wave wv owns local nodes [wv*32, wv*32+32)
    int eg = lane >> 4;      // edge sub-slot 0..3
    int L  = lane & 15;      // feature quad 0..15
    const uint2* sup2 = (const uint2*)support;     // 8 B = 4 bf16 features
    const float4* bias4 = (const float4*)bias;
    float4* out4 = (float4*)out;
    float4 bv = bias4[L];

    for (int nl = wv * 32; nl < wv * 32 + 32; ++nl) {
        int start = loffS[nl], cnt = cntS[nl];
        int endc = min(start + cnt, SMAX);
        int avail = endc > start ? endc - start : 0;
        float4 acc = make_float4(0.f, 0.f, 0.f, 0.f);
        for (int j = 0; j < avail; j += 16) {
            #pragma unroll
            for (int q = 0; q < 4; ++q) {
                int ei = j + q * 4 + eg;
                int2 ed = sE[start + min(ei, avail - 1)];
                float wgt = (ei < avail) ? __int_as_float(ed.y) : 0.f;
                uint2 p = sup2[(long)(ed.x & 0x1FFFF) * 16 + L];
                acc.x += wgt * __uint_as_float(p.x << 16);
                acc.y += wgt * __uint_as_float(p.x & 0xFFFF0000u);
                acc.z += wgt * __uint_as_float(p.y << 16);
                acc.w += wgt * __uint_as_float(p.y & 0xFFFF0000u);
            }
        }
        // reduce across the 4 edge-slot groups
        acc.x += __shfl_xor(acc.x, 16, 64); acc.y += __shfl_xor(acc.y, 16, 64);
        acc.z += __shfl_xor(acc.z, 16, 64); acc.w += __shfl_xor(acc.w, 16, 64);
        acc.x += __shfl_xor(acc.x, 32, 64); acc.y += __shfl_xor(acc.y, 32, 64);
        acc.z += __shfl_xor(acc.z, 32, 64); acc.w += __shfl_xor(acc.w, 32, 64);
        int n = b * BN + nl;
        if (lane < 16 && n < N_NODES) {
            float4 r = make_float4(acc.x + bv.x, acc.y + bv.y,
                                   acc.z + bv.z, acc.w + bv.w);
            out4[(long)n * 16 + L] = r;
        }
    }

    // overflow fallback (correctness only; never taken for this input)
    __syncthreads();
    int no = min(ovfN, OVF);
    for (int i = wv; i < no; i += 4) {
        int2 ed = ovfE[i];
        int s = ed.x & 0x1FFFF, dl = (ed.x >> 17) & 127;
        int n = b * BN + dl;
        if (n < N_NODES) {
            float v = __int_as_float(ed.y) * bf2f(support[(long)s * D + lane]);
            atomicAdd(&out[(long)n * D + lane], v);
        }
    }
}

extern "C" void kernel_launch(void* const* d_in, const int* in_sizes, int n_in,
                              void* d_out, int out_size, void* d_ws, size_t ws_size,
                              hipStream_t stream) {
    const float* x      = (const float*)d_in[0];
    const float* weight = (const float*)d_in[1];
    const float* bias   = (const float*)d_in[2];
    const float* adj    = (const float*)d_in[3];
    const int*   src    = (const int*)d_in[4];
    const int*   dst    = (const int*)d_in[5];
    float* out = (float*)d_out;

    unsigned short* support = (unsigned short*)d_ws;       // 12,800,000 B
    int2* coarse  = (int2*)(support + (long)N_NODES * D);  // 12,800,000 B
    int*  hist    = (int*)(coarse + N_EDGES);              // 800,768 B
    int*  scanned = hist + HLEN;                           // 800,768 B
    int*  bsums   = scanned + HLEN;                        // 1024 B

    hipLaunchKernelGGL(gcn_gemm, dim3(N_NODES * 16 / 2 / 256), dim3(256), 0, stream,
                       x, weight, support);
    hipLaunchKernelGGL(gcn_hist, dim3(HW), dim3(256), 0, stream, dst, hist);
    hipLaunchKernelGGL(gcn_scan1, dim3(NB1), dim3(256), 0, stream,
                       hist, scanned, bsums, HLEN);
    hipLaunchKernelGGL(gcn_scan2, dim3(1), dim3(256), 0, stream, bsums);
    hipLaunchKernelGGL(gcn_scan3, dim3((HLEN + 255) / 256), dim3(256), 0, stream,
                       scanned, bsums, HLEN);
    hipLaunchKernelGGL(gcn_coarse, dim3(HW), dim3(256), 0, stream,
                       src, dst, adj, scanned, coarse);
    hipLaunchKernelGGL(gcn_bgather, dim3(NBUCK), dim3(256), 0, stream,
                       support, coarse, scanned, bias, out);
}

// Round 9
// 222.172 us; speedup vs baseline: 1.0543x; 1.0543x over previous
//
#include <hip/hip_runtime.h>

#define N_NODES 100000
#define N_EDGES 1600000
#define D 64

#define BN 64                               // nodes per bucket
#define NBUCK ((N_NODES + BN - 1) / BN)     // 1563
#define HW 128                              // histogram/scatter chunks
#define HCH ((N_EDGES + HW - 1) / HW)       // 12500 edges per chunk
#define HLEN (NBUCK * HW)                   // 200064
#define NB1 196                             // ceil(HLEN/1024)
#define SMAX 2048                           // LDS edge capacity per bucket (mean 1024)
#define OVF 512                             // overflow list (never used in practice)

static __device__ __forceinline__ unsigned short f2bf(float f) {
    unsigned u = __float_as_uint(f);
    u += 0x7FFFu + ((u >> 16) & 1u);
    return (unsigned short)(u >> 16);
}
static __device__ __forceinline__ float bf2f(unsigned short h) {
    return __uint_as_float((unsigned)h << 16);
}

// ---------------- GEMM: support(bf16) = X @ W ----------------
__global__ __launch_bounds__(256) void gcn_gemm(const float* __restrict__ x,
                                                const float* __restrict__ w,
                                                unsigned short* __restrict__ support) {
    __shared__ float4 wsh[64 * 16];
    int tid = threadIdx.x;
    const float4* w4 = (const float4*)w;
    for (int i = tid; i < 64 * 16; i += 256) wsh[i] = w4[i];
    __syncthreads();

    int idx = blockIdx.x * 256 + tid;
    int rowpair = idx >> 4;
    int c4 = idx & 15;
    long r0 = (long)rowpair * 2;
    const float4* xr0 = (const float4*)(x + r0 * D);
    const float4* xr1 = (const float4*)(x + (r0 + 1) * D);

    float4 a0 = make_float4(0.f, 0.f, 0.f, 0.f);
    float4 a1 = make_float4(0.f, 0.f, 0.f, 0.f);
    #pragma unroll 4
    for (int k4 = 0; k4 < 16; ++k4) {
        float4 xv0 = xr0[k4];
        float4 xv1 = xr1[k4];
        float4 w0 = wsh[(4 * k4 + 0) * 16 + c4];
        float4 w1 = wsh[(4 * k4 + 1) * 16 + c4];
        float4 w2 = wsh[(4 * k4 + 2) * 16 + c4];
        float4 w3 = wsh[(4 * k4 + 3) * 16 + c4];
        a0 += w0 * xv0.x + w1 * xv0.y + w2 * xv0.z + w3 * xv0.w;
        a1 += w0 * xv1.x + w1 * xv1.y + w2 * xv1.z + w3 * xv1.w;
    }
    ushort4* s4 = (ushort4*)support;
    s4[r0 * 16 + c4] = make_ushort4(f2bf(a0.x), f2bf(a0.y), f2bf(a0.z), f2bf(a0.w));
    s4[(r0 + 1) * 16 + c4] = make_ushort4(f2bf(a1.x), f2bf(a1.y), f2bf(a1.z), f2bf(a1.w));
}

// ---------------- per-chunk histogram over buckets ----------------
__global__ __launch_bounds__(256) void gcn_hist(const int* __restrict__ dst,
                                                int* __restrict__ hist) {
    __shared__ int h[NBUCK];
    int tid = threadIdx.x;
    for (int i = tid; i < NBUCK; i += 256) h[i] = 0;
    __syncthreads();
    int w = blockIdx.x;
    int e0 = w * HCH, e1 = min(e0 + HCH, N_EDGES);
    for (int e = e0 + tid; e < e1; e += 256) {
        int d = __builtin_nontemporal_load(&dst[e]);
        atomicAdd(&h[d >> 6], 1);
    }
    __syncthreads();
    for (int c = tid; c < NBUCK; c += 256) hist[c * HW + w] = h[c];
}

// ---------------- exclusive scan of hist ----------------
#define SCAN_B 1024
__global__ __launch_bounds__(256) void gcn_scan1(const int* __restrict__ in,
                                                 int* __restrict__ outp,
                                                 int* __restrict__ bsums, int len) {
    __shared__ int sh[256];
    int tid = threadIdx.x;
    int base = blockIdx.x * SCAN_B + tid * 4;
    int v0 = (base + 0 < len) ? in[base + 0] : 0;
    int v1 = (base + 1 < len) ? in[base + 1] : 0;
    int v2 = (base + 2 < len) ? in[base + 2] : 0;
    int v3 = (base + 3 < len) ? in[base + 3] : 0;
    int local = v0 + v1 + v2 + v3;
    sh[tid] = local;
    __syncthreads();
    for (int off = 1; off < 256; off <<= 1) {
        int t = 0;
        if (tid >= off) t = sh[tid - off];
        __syncthreads();
        if (tid >= off) sh[tid] += t;
        __syncthreads();
    }
    int excl = sh[tid] - local;
    if (base + 0 < len) outp[base + 0] = excl;
    if (base + 1 < len) outp[base + 1] = excl + v0;
    if (base + 2 < len) outp[base + 2] = excl + v0 + v1;
    if (base + 3 < len) outp[base + 3] = excl + v0 + v1 + v2;
    if (tid == 255) bsums[blockIdx.x] = sh[255];
}

__global__ __launch_bounds__(256) void gcn_scan2(int* __restrict__ bsums) {
    __shared__ int sh[256];
    int tid = threadIdx.x;
    int orig = (tid < NB1) ? bsums[tid] : 0;
    sh[tid] = orig;
    __syncthreads();
    for (int off = 1; off < 256; off <<= 1) {
        int t = 0;
        if (tid >= off) t = sh[tid - off];
        __syncthreads();
        if (tid >= off) sh[tid] += t;
        __syncthreads();
    }
    if (tid < NB1) bsums[tid] = sh[tid] - orig;  // exclusive
}

__global__ __launch_bounds__(256) void gcn_scan3(int* __restrict__ data,
                                                 const int* __restrict__ bsums, int len) {
    int i = blockIdx.x * 256 + threadIdx.x;
    if (i < len) data[i] += bsums[i >> 10];
}

// ---------------- coarse scatter: bucket-sorted edges (runs ~16 = 128 B) ----------------
__global__ __launch_bounds__(256) void gcn_coarse(const int* __restrict__ src,
                                                  const int* __restrict__ dst,
                                                  const float* __restrict__ adj,
                                                  const int* __restrict__ base,
                                                  int2* __restrict__ coarse) {
    __shared__ int cur[NBUCK];
    int tid = threadIdx.x;
    int w = blockIdx.x;
    for (int c = tid; c < NBUCK; c += 256) cur[c] = base[c * HW + w];
    __syncthreads();
    int e0 = w * HCH, e1 = min(e0 + HCH, N_EDGES);
    for (int e = e0 + tid; e < e1; e += 256) {
        int d = __builtin_nontemporal_load(&dst[e]);
        int s = __builtin_nontemporal_load(&src[e]);
        float a = __builtin_nontemporal_load(&adj[e]);
        int pos = atomicAdd(&cur[d >> 6], 1);
        coarse[pos] = make_int2(s | ((d & 63) << 17), __float_as_int(a));
    }
}

// ---------------- fused: per-bucket LDS counting sort + wide gather ----------------
__global__ __launch_bounds__(256) void gcn_bgather(const unsigned short* __restrict__ support,
                                                   const int2* __restrict__ coarse,
                                                   const int* __restrict__ base,
                                                   const float* __restrict__ bias,
                                                   float* __restrict__ out) {
    __shared__ int2 sE[SMAX];       // 16 KB sorted edges
    __shared__ int2 ovfE[OVF];      // 4 KB overflow (never used in practice)
    __shared__ int cntS[BN], loffS[BN], curS[BN];
    __shared__ int ovfN;

    int tid = threadIdx.x, wv = tid >> 6, lane = tid & 63;
    int b = blockIdx.x;
    int e0 = base[b * HW];
    int e1 = (b == NBUCK - 1) ? N_EDGES : base[(b + 1) * HW];

    if (tid < BN) cntS[tid] = 0;
    if (tid == 0) ovfN = 0;
    __syncthreads();

    // phase A: count per-node
    for (int e = e0 + tid; e < e1; e += 256)
        atomicAdd(&cntS[(coarse[e].x >> 17) & 63], 1);
    __syncthreads();

    // scan 64 counters
    if (tid < BN) loffS[tid] = cntS[tid];
    __syncthreads();
    for (int off = 1; off < BN; off <<= 1) {
        int t = 0;
        if (tid < BN && tid >= off) t = loffS[tid - off];
        __syncthreads();
        if (tid < BN && tid >= off) loffS[tid] += t;
        __syncthreads();
    }
    if (tid < BN) {
        int excl = loffS[tid] - cntS[tid];
        loffS[tid] = excl;
        curS[tid] = excl;
    }
    __syncthreads();

    // phase B: place edges into LDS per-node-sorted (window re-read hits L2)
    for (int e = e0 + tid; e < e1; e += 256) {
        int2 ed = coarse[e];
        int nl = (ed.x >> 17) & 63;
        int pos = atomicAdd(&curS[nl], 1);
        if (pos < SMAX) sE[pos] = ed;
        else {
            int op = atomicAdd(&ovfN, 1);
            if (op < OVF) ovfE[op] = ed;
        }
    }
    __syncthreads();

    // gather: wave wv owns local nodes [wv*16, wv*16+16)
    int eg = lane >> 4;      // edge sub-slot 0..3
    int L  = lane & 15;      // feature quad 0..15
    const uint2* sup2 = (const uint2*)support;     // 8 B = 4 bf16 features
    const float4* bias4 = (const float4*)bias;
    float4* out4 = (float4*)out;
    float4 bv = bias4[L];

    for (int nl = wv * 16; nl < wv * 16 + 16; ++nl) {
        int start = loffS[nl], cnt = cntS[nl];
        int endc = min(start + cnt, SMAX);
        int avail = endc > start ? endc - start : 0;
        float4 acc = make_float4(0.f, 0.f, 0.f, 0.f);
        for (int j = 0; j < avail; j += 16) {
            #pragma unroll
            for (int q = 0; q < 4; ++q) {
                int ei = j + q * 4 + eg;
                int2 ed = sE[start + min(ei, avail - 1)];
                float wgt = (ei < avail) ? __int_as_float(ed.y) : 0.f;
                uint2 p = sup2[(long)(ed.x & 0x1FFFF) * 16 + L];
                acc.x += wgt * __uint_as_float(p.x << 16);
                acc.y += wgt * __uint_as_float(p.x & 0xFFFF0000u);
                acc.z += wgt * __uint_as_float(p.y << 16);
                acc.w += wgt * __uint_as_float(p.y & 0xFFFF0000u);
            }
        }
        // reduce across the 4 edge-slot groups
        acc.x += __shfl_xor(acc.x, 16, 64); acc.y += __shfl_xor(acc.y, 16, 64);
        acc.z += __shfl_xor(acc.z, 16, 64); acc.w += __shfl_xor(acc.w, 16, 64);
        acc.x += __shfl_xor(acc.x, 32, 64); acc.y += __shfl_xor(acc.y, 32, 64);
        acc.z += __shfl_xor(acc.z, 32, 64); acc.w += __shfl_xor(acc.w, 32, 64);
        int n = b * BN + nl;
        if (lane < 16 && n < N_NODES) {
            float4 r = make_float4(acc.x + bv.x, acc.y + bv.y,
                                   acc.z + bv.z, acc.w + bv.w);
            out4[(long)n * 16 + L] = r;
        }
    }

    // overflow fallback (correctness only; never taken for this input)
    __syncthreads();
    int no = min(ovfN, OVF);
    for (int i = wv; i < no; i += 4) {
        int2 ed = ovfE[i];
        int s = ed.x & 0x1FFFF, dl = (ed.x >> 17) & 63;
        int n = b * BN + dl;
        if (n < N_NODES) {
            float v = __int_as_float(ed.y) * bf2f(support[(long)s * D + lane]);
            atomicAdd(&out[(long)n * D + lane], v);
        }
    }
}

extern "C" void kernel_launch(void* const* d_in, const int* in_sizes, int n_in,
                              void* d_out, int out_size, void* d_ws, size_t ws_size,
                              hipStream_t stream) {
    const float* x      = (const float*)d_in[0];
    const float* weight = (const float*)d_in[1];
    const float* bias   = (const float*)d_in[2];
    const float* adj    = (const float*)d_in[3];
    const int*   src    = (const int*)d_in[4];
    const int*   dst    = (const int*)d_in[5];
    float* out = (float*)d_out;

    unsigned short* support = (unsigned short*)d_ws;       // 12,800,000 B
    int2* coarse  = (int2*)(support + (long)N_NODES * D);  // 12,800,000 B
    int*  hist    = (int*)(coarse + N_EDGES);              // 800,256 B
    int*  scanned = hist + HLEN;                           // 800,256 B
    int*  bsums   = scanned + HLEN;                        // 1024 B

    hipLaunchKernelGGL(gcn_gemm, dim3(N_NODES * 16 / 2 / 256), dim3(256), 0, stream,
                       x, weight, support);
    hipLaunchKernelGGL(gcn_hist, dim3(HW), dim3(256), 0, stream, dst, hist);
    hipLaunchKernelGGL(gcn_scan1, dim3(NB1), dim3(256), 0, stream,
                       hist, scanned, bsums, HLEN);
    hipLaunchKernelGGL(gcn_scan2, dim3(1), dim3(256), 0, stream, bsums);
    hipLaunchKernelGGL(gcn_scan3, dim3((HLEN + 255) / 256), dim3(256), 0, stream,
                       scanned, bsums, HLEN);
    hipLaunchKernelGGL(gcn_coarse, dim3(HW), dim3(256), 0, stream,
                       src, dst, adj, scanned, coarse);
    hipLaunchKernelGGL(gcn_bgather, dim3(NBUCK), dim3(256), 0, stream,
                       support, coarse, scanned, bias, out);
}

// Round 10
// 211.472 us; speedup vs baseline: 1.1076x; 1.0506x over previous
//
#include <hip/hip_runtime.h>

#define N_NODES 100000
#define N_EDGES 1600000
#define D 64

#define BN 64                               // nodes per bucket
#define NBUCK ((N_NODES + BN - 1) / BN)     // 1563
#define CHW 256                             // coarse/count chunks (blocks)
#define CH ((N_EDGES + CHW - 1) / CHW)      // 6250 edges per chunk
#define CITER 13                            // ceil(CH/512)
#define SMAX 2048                           // LDS edge capacity per bucket (mean 1024)
#define OVF 512                             // overflow list (never used in practice)
#define PAD 16                              // cursor padding (64 B) -> per-line atomics

static __device__ __forceinline__ unsigned short f2bf(float f) {
    unsigned u = __float_as_uint(f);
    u += 0x7FFFu + ((u >> 16) & 1u);
    return (unsigned short)(u >> 16);
}
static __device__ __forceinline__ float bf2f(unsigned short h) {
    return __uint_as_float((unsigned)h << 16);
}

// ---------------- GEMM: support(bf16) = X @ W ----------------
__global__ __launch_bounds__(256) void gcn_gemm(const float* __restrict__ x,
                                                const float* __restrict__ w,
                                                unsigned short* __restrict__ support) {
    __shared__ float4 wsh[64 * 16];
    int tid = threadIdx.x;
    const float4* w4 = (const float4*)w;
    for (int i = tid; i < 64 * 16; i += 256) wsh[i] = w4[i];
    __syncthreads();

    int idx = blockIdx.x * 256 + tid;
    int rowpair = idx >> 4;
    int c4 = idx & 15;
    long r0 = (long)rowpair * 2;
    const float4* xr0 = (const float4*)(x + r0 * D);
    const float4* xr1 = (const float4*)(x + (r0 + 1) * D);

    float4 a0 = make_float4(0.f, 0.f, 0.f, 0.f);
    float4 a1 = make_float4(0.f, 0.f, 0.f, 0.f);
    #pragma unroll 4
    for (int k4 = 0; k4 < 16; ++k4) {
        float4 xv0 = xr0[k4];
        float4 xv1 = xr1[k4];
        float4 w0 = wsh[(4 * k4 + 0) * 16 + c4];
        float4 w1 = wsh[(4 * k4 + 1) * 16 + c4];
        float4 w2 = wsh[(4 * k4 + 2) * 16 + c4];
        float4 w3 = wsh[(4 * k4 + 3) * 16 + c4];
        a0 += w0 * xv0.x + w1 * xv0.y + w2 * xv0.z + w3 * xv0.w;
        a1 += w0 * xv1.x + w1 * xv1.y + w2 * xv1.z + w3 * xv1.w;
    }
    ushort4* s4 = (ushort4*)support;
    s4[r0 * 16 + c4] = make_ushort4(f2bf(a0.x), f2bf(a0.y), f2bf(a0.z), f2bf(a0.w));
    s4[(r0 + 1) * 16 + c4] = make_ushort4(f2bf(a1.x), f2bf(a1.y), f2bf(a1.z), f2bf(a1.w));
}

// ---------------- bucket totals: per-block LDS hist -> padded global atomics ----------------
__global__ __launch_bounds__(512) void gcn_bcount(const int* __restrict__ dst,
                                                  int* __restrict__ btot) {
    __shared__ int h[NBUCK];
    int tid = threadIdx.x;
    for (int i = tid; i < NBUCK; i += 512) h[i] = 0;
    __syncthreads();
    int e0 = blockIdx.x * CH, e1 = min(e0 + CH, N_EDGES);
    for (int e = e0 + tid; e < e1; e += 512) {
        int d = __builtin_nontemporal_load(&dst[e]);
        atomicAdd(&h[d >> 6], 1);
    }
    __syncthreads();
    for (int i = tid; i < NBUCK; i += 512)
        if (h[i]) atomicAdd(&btot[i * PAD], h[i]);
}

// ---------------- scan bucket totals -> sbase, seed padded cursors ----------------
__global__ __launch_bounds__(1024) void gcn_bscan(const int* __restrict__ btot,
                                                  int* __restrict__ sbase,
                                                  int* __restrict__ gcur) {
    __shared__ int sh[1024];
    int tid = threadIdx.x;
    int i0 = 2 * tid, i1 = 2 * tid + 1;
    int t0 = (i0 < NBUCK) ? btot[i0 * PAD] : 0;
    int t1 = (i1 < NBUCK) ? btot[i1 * PAD] : 0;
    int local = t0 + t1;
    sh[tid] = local;
    __syncthreads();
    for (int off = 1; off < 1024; off <<= 1) {
        int t = 0;
        if (tid >= off) t = sh[tid - off];
        __syncthreads();
        if (tid >= off) sh[tid] += t;
        __syncthreads();
    }
    int excl = sh[tid] - local;
    if (i0 < NBUCK) { sbase[i0] = excl;      gcur[i0 * PAD] = excl; }
    if (i1 < NBUCK) { sbase[i1] = excl + t0; gcur[i1 * PAD] = excl + t0; }
    if (tid == 1023) sbase[NBUCK] = sh[1023];
}

// ---------------- coarse: register-staged chunk, per-block run reservation ----------------
__global__ __launch_bounds__(512) void gcn_coarse(const int* __restrict__ src,
                                                  const int* __restrict__ dst,
                                                  const float* __restrict__ adj,
                                                  int* __restrict__ gcur,
                                                  int2* __restrict__ coarse) {
    __shared__ int h[NBUCK];
    __shared__ int cur[NBUCK];
    int tid = threadIdx.x, w = blockIdx.x;
    for (int i = tid; i < NBUCK; i += 512) h[i] = 0;
    __syncthreads();

    int e0 = w * CH, e1 = min(e0 + CH, N_EDGES);
    int dreg[CITER], sreg[CITER];
    float areg[CITER];
    #pragma unroll
    for (int it = 0; it < CITER; ++it) {
        int e = e0 + tid + it * 512;
        dreg[it] = -1;
        if (e < e1) {
            dreg[it] = __builtin_nontemporal_load(&dst[e]);
            sreg[it] = __builtin_nontemporal_load(&src[e]);
            areg[it] = __builtin_nontemporal_load(&adj[e]);
            atomicAdd(&h[dreg[it] >> 6], 1);
        }
    }
    __syncthreads();

    for (int c = tid; c < NBUCK; c += 512) {
        int hc = h[c];
        if (hc) cur[c] = atomicAdd(&gcur[c * PAD], hc);
    }
    __syncthreads();

    #pragma unroll
    for (int it = 0; it < CITER; ++it) {
        if (dreg[it] >= 0) {
            int c = dreg[it] >> 6;
            int pos = atomicAdd(&cur[c], 1);
            coarse[pos] = make_int2(sreg[it] | ((dreg[it] & 63) << 17),
                                    __float_as_int(areg[it]));
        }
    }
}

// ---------------- fused: per-bucket LDS counting sort + wide gather ----------------
__global__ __launch_bounds__(256) void gcn_bgather(const unsigned short* __restrict__ support,
                                                   const int2* __restrict__ coarse,
                                                   const int* __restrict__ sbase,
                                                   const float* __restrict__ bias,
                                                   float* __restrict__ out) {
    __shared__ int2 sE[SMAX];       // 16 KB sorted edges
    __shared__ int2 ovfE[OVF];      // 4 KB overflow (never used in practice)
    __shared__ int cntS[BN], loffS[BN], curS[BN];
    __shared__ int ovfN;

    int tid = threadIdx.x, wv = tid >> 6, lane = tid & 63;
    int b = blockIdx.x;
    int e0 = sbase[b];
    int e1 = sbase[b + 1];

    if (tid < BN) cntS[tid] = 0;
    if (tid == 0) ovfN = 0;
    __syncthreads();

    // phase A: count per-node
    for (int e = e0 + tid; e < e1; e += 256)
        atomicAdd(&cntS[(coarse[e].x >> 17) & 63], 1);
    __syncthreads();

    // scan 64 counters
    if (tid < BN) loffS[tid] = cntS[tid];
    __syncthreads();
    for (int off = 1; off < BN; off <<= 1) {
        int t = 0;
        if (tid < BN && tid >= off) t = loffS[tid - off];
        __syncthreads();
        if (tid < BN && tid >= off) loffS[tid] += t;
        __syncthreads();
    }
    if (tid < BN) {
        int excl = loffS[tid] - cntS[tid];
        loffS[tid] = excl;
        curS[tid] = excl;
    }
    __syncthreads();

    // phase B: place edges into LDS per-node-sorted (window re-read hits L2)
    for (int e = e0 + tid; e < e1; e += 256) {
        int2 ed = coarse[e];
        int nl = (ed.x >> 17) & 63;
        int pos = atomicAdd(&curS[nl], 1);
        if (pos < SMAX) sE[pos] = ed;
        else {
            int op = atomicAdd(&ovfN, 1);
            if (op < OVF) ovfE[op] = ed;
        }
    }
    __syncthreads();

    // gather: wave wv owns local nodes [wv*16, wv*16+16)
    int eg = lane >> 4;      // edge sub-slot 0..3
    int L  = lane & 15;      // feature quad 0..15
    const uint2* sup2 = (const uint2*)support;     // 8 B = 4 bf16 features
    const float4* bias4 = (const float4*)bias;
    float4* out4 = (float4*)out;
    float4 bv = bias4[L];

    for (int nl = wv * 16; nl < wv * 16 + 16; ++nl) {
        int start = loffS[nl], cnt = cntS[nl];
        int endc = min(start + cnt, SMAX);
        int avail = endc > start ? endc - start : 0;
        float4 acc = make_float4(0.f, 0.f, 0.f, 0.f);
        for (int j = 0; j < avail; j += 16) {
            #pragma unroll
            for (int q = 0; q < 4; ++q) {
                int ei = j + q * 4 + eg;
                int2 ed = sE[start + min(ei, avail - 1)];
                float wgt = (ei < avail) ? __int_as_float(ed.y) : 0.f;
                uint2 p = sup2[(long)(ed.x & 0x1FFFF) * 16 + L];
                acc.x += wgt * __uint_as_float(p.x << 16);
                acc.y += wgt * __uint_as_float(p.x & 0xFFFF0000u);
                acc.z += wgt * __uint_as_float(p.y << 16);
                acc.w += wgt * __uint_as_float(p.y & 0xFFFF0000u);
            }
        }
        // reduce across the 4 edge-slot groups
        acc.x += __shfl_xor(acc.x, 16, 64); acc.y += __shfl_xor(acc.y, 16, 64);
        acc.z += __shfl_xor(acc.z, 16, 64); acc.w += __shfl_xor(acc.w, 16, 64);
        acc.x += __shfl_xor(acc.x, 32, 64); acc.y += __shfl_xor(acc.y, 32, 64);
        acc.z += __shfl_xor(acc.z, 32, 64); acc.w += __shfl_xor(acc.w, 32, 64);
        int n = b * BN + nl;
        if (lane < 16 && n < N_NODES) {
            float4 r = make_float4(acc.x + bv.x, acc.y + bv.y,
                                   acc.z + bv.z, acc.w + bv.w);
            out4[(long)n * 16 + L] = r;
        }
    }

    // overflow fallback (correctness only; never taken for this input)
    __syncthreads();
    int no = min(ovfN, OVF);
    for (int i = wv; i < no; i += 4) {
        int2 ed = ovfE[i];
        int s = ed.x & 0x1FFFF, dl = (ed.x >> 17) & 63;
        int n = b * BN + dl;
        if (n < N_NODES) {
            float v = __int_as_float(ed.y) * bf2f(support[(long)s * D + lane]);
            atomicAdd(&out[(long)n * D + lane], v);
        }
    }
}

extern "C" void kernel_launch(void* const* d_in, const int* in_sizes, int n_in,
                              void* d_out, int out_size, void* d_ws, size_t ws_size,
                              hipStream_t stream) {
    const float* x      = (const float*)d_in[0];
    const float* weight = (const float*)d_in[1];
    const float* bias   = (const float*)d_in[2];
    const float* adj    = (const float*)d_in[3];
    const int*   src    = (const int*)d_in[4];
    const int*   dst    = (const int*)d_in[5];
    float* out = (float*)d_out;

    unsigned short* support = (unsigned short*)d_ws;       // 12,800,000 B
    int2* coarse = (int2*)(support + (long)N_NODES * D);   // 12,800,000 B
    int*  btot   = (int*)(coarse + N_EDGES);               // NBUCK*PAD*4 = 100,032 B
    int*  gcur   = btot + NBUCK * PAD;                     // 100,032 B
    int*  sbase  = gcur + NBUCK * PAD;                     // (NBUCK+1)*4 B

    hipLaunchKernelGGL(gcn_gemm, dim3(N_NODES * 16 / 2 / 256), dim3(256), 0, stream,
                       x, weight, support);
    hipMemsetAsync(btot, 0, NBUCK * PAD * sizeof(int), stream);
    hipLaunchKernelGGL(gcn_bcount, dim3(CHW), dim3(512), 0, stream, dst, btot);
    hipLaunchKernelGGL(gcn_bscan, dim3(1), dim3(1024), 0, stream, btot, sbase, gcur);
    hipLaunchKernelGGL(gcn_coarse, dim3(CHW), dim3(512), 0, stream,
                       src, dst, adj, gcur, coarse);
    hipLaunchKernelGGL(gcn_bgather, dim3(NBUCK), dim3(256), 0, stream,
                       support, coarse, sbase, bias, out);
}